// Round 1
// baseline (196.740 us; speedup 1.0000x reference)
//
#include <hip/hip_runtime.h>
#include <hip/hip_bf16.h>
#include <cstddef>

typedef __bf16 bf16;
typedef __bf16 bf16x8 __attribute__((ext_vector_type(8)));
typedef float  f32x4  __attribute__((ext_vector_type(4)));

#define NC   128
#define NS   6144
#define HD   32
#define BKV  128
#define GELEMS (16 * NS)   // elements per group-norm group

__device__ __forceinline__ f32x4 mfma16(bf16x8 a, bf16x8 b, f32x4 c) {
  return __builtin_amdgcn_mfma_f32_16x16x32_bf16(a, b, c, 0, 0, 0);
}

// ---- k0: convert weights to bf16; fold attn scale (32^-0.5) into Wq, bq ----
__global__ void k_prep(const float* __restrict__ qkv_w, const float* __restrict__ qkv_b,
                       const float* __restrict__ proj_w,
                       bf16* __restrict__ wq, bf16* __restrict__ wp, float* __restrict__ bias_s) {
  int i = blockIdx.x * 256 + threadIdx.x;
  const float scale = 0.1767766952966369f;
  if (i < 3 * NC * NC) {
    float v = qkv_w[i];
    if ((i >> 7) < NC) v *= scale;      // q rows
    wq[i] = (bf16)v;
  }
  if (i < NC * NC) wp[i] = (bf16)proj_w[i];
  if (i < 3 * NC) bias_s[i] = qkv_b[i] * ((i < NC) ? scale : 1.0f);
}

// ---- k1: group-norm partial sums: grid = 8 groups x 12 chunks ----
__global__ __launch_bounds__(256) void k_gnstats(const float* __restrict__ x, float* __restrict__ partials) {
  int g = blockIdx.x / 12, chunk = blockIdx.x % 12;
  int tid = threadIdx.x;
  float sum = 0.f, sq = 0.f;
  #pragma unroll
  for (int k = 0; k < 8; ++k) {
    int f4 = tid + k * 256;            // 0..2047 -> 16 ch x 128 float4
    int c  = f4 >> 7;
    int s4 = f4 & 127;
    const float4 v = ((const float4*)x)[(size_t)(g * 16 + c) * (NS / 4) + chunk * 128 + s4];
    sum += v.x + v.y + v.z + v.w;
    sq  += v.x * v.x + v.y * v.y + v.z * v.z + v.w * v.w;
  }
  #pragma unroll
  for (int off = 32; off; off >>= 1) {
    sum += __shfl_down(sum, off, 64);
    sq  += __shfl_down(sq,  off, 64);
  }
  __shared__ float red[2][4];
  if ((tid & 63) == 0) { red[0][tid >> 6] = sum; red[1][tid >> 6] = sq; }
  __syncthreads();
  if (tid == 0) {
    partials[blockIdx.x * 2 + 0] = red[0][0] + red[0][1] + red[0][2] + red[0][3];
    partials[blockIdx.x * 2 + 1] = red[1][0] + red[1][1] + red[1][2] + red[1][3];
  }
}

// ---- k2: apply group norm, write transposed xn_t[s][c] in bf16 ----
__global__ __launch_bounds__(256) void k_gnapply(const float* __restrict__ x, const float* __restrict__ partials,
                                                 const float* __restrict__ gn_w, const float* __restrict__ gn_b,
                                                 bf16* __restrict__ xnt) {
  int bid = blockIdx.x;
  int c2 = bid & 63;       // pair of channels
  int sb = bid >> 6;       // 0..11 (512-wide s slabs)
  int c0 = c2 * 2;
  int g  = c0 >> 4;
  float sum = 0.f, sq = 0.f;
  #pragma unroll
  for (int i = 0; i < 12; ++i) {
    sum += partials[(g * 12 + i) * 2 + 0];
    sq  += partials[(g * 12 + i) * 2 + 1];
  }
  float mean = sum * (1.0f / GELEMS);
  float var  = sq  * (1.0f / GELEMS) - mean * mean;
  float rstd = rsqrtf(var + 1e-5f);
  int t = threadIdx.x;
  #pragma unroll
  for (int cc = 0; cc < 2; ++cc) {
    int c = c0 + cc;
    float wc = gn_w[c] * rstd;
    float bc = gn_b[c] - mean * wc;
    float2 v = ((const float2*)(x + (size_t)c * NS + sb * 512))[t];
    int s = sb * 512 + t * 2;
    xnt[(size_t)s * NC + c]       = (bf16)(v.x * wc + bc);
    xnt[(size_t)(s + 1) * NC + c] = (bf16)(v.y * wc + bc);
  }
}

// ---- k3: QKV GEMM (M=384 o, N=6144 s, K=128), bf16 MFMA, direct-global frags ----
__global__ __launch_bounds__(256) void k_qkv(const bf16* __restrict__ wq, const bf16* __restrict__ xnt,
                                             const float* __restrict__ bias_s, bf16* __restrict__ qkv) {
  int ot = blockIdx.x;            // 0..5
  int st = blockIdx.y;            // 0..95
  int w = threadIdx.x >> 6, l = threadIdx.x & 63;
  int lr = l & 15, lg = l >> 4;
  int o_base = ot * 64 + (w >> 1) * 32;
  int s_base = st * 64 + (w & 1) * 32;
  f32x4 acc[2][2] = {};
  #pragma unroll
  for (int k0 = 0; k0 < NC; k0 += 32) {
    bf16x8 a[2], b[2];
    #pragma unroll
    for (int m = 0; m < 2; ++m)
      a[m] = *(const bf16x8*)(wq + (size_t)(o_base + m * 16 + lr) * NC + k0 + lg * 8);
    #pragma unroll
    for (int n = 0; n < 2; ++n)
      b[n] = *(const bf16x8*)(xnt + (size_t)(s_base + n * 16 + lr) * NC + k0 + lg * 8);
    #pragma unroll
    for (int m = 0; m < 2; ++m)
      #pragma unroll
      for (int n = 0; n < 2; ++n)
        acc[m][n] = mfma16(a[m], b[n], acc[m][n]);
  }
  #pragma unroll
  for (int m = 0; m < 2; ++m)
    #pragma unroll
    for (int n = 0; n < 2; ++n)
      #pragma unroll
      for (int r = 0; r < 4; ++r) {
        int o = o_base + m * 16 + lg * 4 + r;
        int s = s_base + n * 16 + lr;
        float v = acc[m][n][r] + bias_s[o];
        int which = o >> 7, rem = o & 127, head = rem >> 5, c32 = rem & 31;
        qkv[((size_t)(which * 4 + head) * NS + s) * HD + c32] = (bf16)v;
      }
}

// ---- k4: flash attention, 4 waves x 16 q-rows per block, 128-key chunks ----
__global__ __launch_bounds__(256) void k_attn(const bf16* __restrict__ qkv, bf16* __restrict__ attn) {
  int h  = blockIdx.y;
  int q0 = blockIdx.x * 64;
  int tid = threadIdx.x;
  int w = tid >> 6, l = tid & 63;
  int lr = l & 15, lg = l >> 4;

  __shared__ bf16 kb[BKV][40];          // K chunk, padded rows (80B: 2-way max)
  __shared__ bf16 vt[HD][BKV + 8];      // V chunk transposed, padded (272B rows)
  __shared__ bf16 pb[4][16][BKV + 8];   // per-wave P tile

  const bf16* qp = qkv + (size_t)(0 + h) * NS * HD;
  const bf16* kp = qkv + (size_t)(4 + h) * NS * HD;
  const bf16* vp = qkv + (size_t)(8 + h) * NS * HD;

  // Q fragment: A[m=lr][k=lg*8+j], rows q0+w*16+lr (q pre-scaled by 32^-0.5)
  bf16x8 qf = *(const bf16x8*)(qp + (size_t)(q0 + w * 16 + lr) * HD + lg * 8);

  f32x4 acc0 = {}, acc1 = {};
  float mrun[4], lrun[4];
  #pragma unroll
  for (int r = 0; r < 4; ++r) { mrun[r] = -1e30f; lrun[r] = 0.f; }
  const f32x4 zed = {};

  for (int kv0 = 0; kv0 < NS; kv0 += BKV) {
    __syncthreads();
    #pragma unroll
    for (int it = 0; it < 2; ++it) {
      int t2 = tid + it * 256;          // 0..511
      int key = t2 >> 2;                // 0..127
      int c8  = (t2 & 3) << 3;          // 0,8,16,24
      *(bf16x8*)(&kb[key][c8]) = *(const bf16x8*)(kp + (size_t)(kv0 + key) * HD + c8);
      bf16x8 vv = *(const bf16x8*)(vp + (size_t)(kv0 + key) * HD + c8);
      #pragma unroll
      for (int j = 0; j < 8; ++j) vt[c8 + j][key] = vv[j];
    }
    __syncthreads();

    // QK^T: 8 tiles of 16 keys
    f32x4 sv[BKV / 16];
    #pragma unroll
    for (int t = 0; t < BKV / 16; ++t) {
      bf16x8 kf = *(const bf16x8*)(&kb[t * 16 + lr][lg * 8]);
      sv[t] = mfma16(qf, kf, zed);
    }

    // online softmax (rows lg*4+r, cols across 16-lane group)
    #pragma unroll
    for (int r = 0; r < 4; ++r) {
      float mx = sv[0][r];
      #pragma unroll
      for (int t = 1; t < BKV / 16; ++t) mx = fmaxf(mx, sv[t][r]);
      #pragma unroll
      for (int off = 1; off < 16; off <<= 1) mx = fmaxf(mx, __shfl_xor(mx, off, 16));
      float mn  = fmaxf(mrun[r], mx);
      float esc = __expf(mrun[r] - mn);
      float rs = 0.f;
      #pragma unroll
      for (int t = 0; t < BKV / 16; ++t) {
        float e = __expf(sv[t][r] - mn);
        sv[t][r] = e;
        rs += e;
      }
      #pragma unroll
      for (int off = 1; off < 16; off <<= 1) rs += __shfl_xor(rs, off, 16);
      lrun[r] = lrun[r] * esc + rs;
      mrun[r] = mn;
      acc0[r] *= esc;
      acc1[r] *= esc;
    }

    // P -> LDS (bf16), then PV
    #pragma unroll
    for (int t = 0; t < BKV / 16; ++t)
      #pragma unroll
      for (int r = 0; r < 4; ++r)
        pb[w][lg * 4 + r][t * 16 + lr] = (bf16)sv[t][r];

    #pragma unroll
    for (int kk = 0; kk < BKV / 32; ++kk) {
      bf16x8 pf = *(const bf16x8*)(&pb[w][lr][kk * 32 + lg * 8]);
      bf16x8 v0 = *(const bf16x8*)(&vt[lr][kk * 32 + lg * 8]);
      bf16x8 v1 = *(const bf16x8*)(&vt[16 + lr][kk * 32 + lg * 8]);
      acc0 = mfma16(pf, v0, acc0);
      acc1 = mfma16(pf, v1, acc1);
    }
  }

  #pragma unroll
  for (int r = 0; r < 4; ++r) {
    float inv = 1.0f / lrun[r];
    int srow = q0 + w * 16 + lg * 4 + r;
    attn[(size_t)srow * NC + h * HD + lr]      = (bf16)(acc0[r] * inv);
    attn[(size_t)srow * NC + h * HD + 16 + lr] = (bf16)(acc1[r] * inv);
  }
}

// ---- k5: proj GEMM (M=128, N=6144, K=128) + bias + residual + mask ----
__global__ __launch_bounds__(256) void k_proj(const bf16* __restrict__ wp, const bf16* __restrict__ attn,
                                              const float* __restrict__ proj_b, const float* __restrict__ x,
                                              const float* __restrict__ mask, float* __restrict__ out) {
  int ot = blockIdx.x;            // 0..1
  int st = blockIdx.y;            // 0..95
  int w = threadIdx.x >> 6, l = threadIdx.x & 63;
  int lr = l & 15, lg = l >> 4;
  int o_base = ot * 64 + (w >> 1) * 32;
  int s_base = st * 64 + (w & 1) * 32;
  f32x4 acc[2][2] = {};
  #pragma unroll
  for (int k0 = 0; k0 < NC; k0 += 32) {
    bf16x8 a[2], b[2];
    #pragma unroll
    for (int m = 0; m < 2; ++m)
      a[m] = *(const bf16x8*)(wp + (size_t)(o_base + m * 16 + lr) * NC + k0 + lg * 8);
    #pragma unroll
    for (int n = 0; n < 2; ++n)
      b[n] = *(const bf16x8*)(attn + (size_t)(s_base + n * 16 + lr) * NC + k0 + lg * 8);
    #pragma unroll
    for (int m = 0; m < 2; ++m)
      #pragma unroll
      for (int n = 0; n < 2; ++n)
        acc[m][n] = mfma16(a[m], b[n], acc[m][n]);
  }
  #pragma unroll
  for (int m = 0; m < 2; ++m)
    #pragma unroll
    for (int n = 0; n < 2; ++n)
      #pragma unroll
      for (int r = 0; r < 4; ++r) {
        int o = o_base + m * 16 + lg * 4 + r;
        int s = s_base + n * 16 + lr;
        float v = acc[m][n][r] + proj_b[o] + x[(size_t)o * NS + s];
        out[(size_t)o * NS + s] = v * mask[s];
      }
}

extern "C" void kernel_launch(void* const* d_in, const int* in_sizes, int n_in,
                              void* d_out, int out_size, void* d_ws, size_t ws_size,
                              hipStream_t stream) {
  const float* x      = (const float*)d_in[0];
  const float* mask   = (const float*)d_in[1];
  const float* gn_w   = (const float*)d_in[2];
  const float* gn_b   = (const float*)d_in[3];
  const float* qkv_w  = (const float*)d_in[4];
  const float* qkv_b  = (const float*)d_in[5];
  const float* proj_w = (const float*)d_in[6];
  const float* proj_b = (const float*)d_in[7];

  char* ws = (char*)d_ws;
  float* partials = (float*)(ws + 0);            //   768 B
  float* bias_s   = (float*)(ws + 1024);         //  1536 B
  bf16*  wq       = (bf16*)(ws + 4096);          // 98304 B
  bf16*  wp       = (bf16*)(ws + 102400);        // 32768 B
  bf16*  xnt      = (bf16*)(ws + 135168);        // 1.5 MB  [s][c]
  bf16*  qkvb     = (bf16*)(ws + 1708032);       // 4.5 MB  [12][s][32]
  bf16*  attn     = (bf16*)(ws + 6426624);       // 1.5 MB  [s][c]
  float* out      = (float*)d_out;

  k_prep   <<<192, 256, 0, stream>>>(qkv_w, qkv_b, proj_w, wq, wp, bias_s);
  k_gnstats<<<96, 256, 0, stream>>>(x, partials);
  k_gnapply<<<768, 256, 0, stream>>>(x, partials, gn_w, gn_b, xnt);
  k_qkv    <<<dim3(6, 96), 256, 0, stream>>>(wq, xnt, bias_s, qkvb);
  k_attn   <<<dim3(96, 4), 256, 0, stream>>>(qkvb, attn);
  k_proj   <<<dim3(2, 96), 256, 0, stream>>>(wp, attn, proj_b, x, mask, out);
  hipMemcpyAsync(out + (size_t)NC * NS, mask, NS * sizeof(float),
                 hipMemcpyDeviceToDevice, stream);
}

// Round 2
// 149.682 us; speedup vs baseline: 1.3144x; 1.3144x over previous
//
#include <hip/hip_runtime.h>
#include <hip/hip_bf16.h>
#include <cstddef>

typedef __bf16 bf16;
typedef __bf16 bf16x4 __attribute__((ext_vector_type(4)));
typedef __bf16 bf16x8 __attribute__((ext_vector_type(8)));
typedef float  f32x4  __attribute__((ext_vector_type(4)));

#define NC   128
#define NS   6144
#define HD   32
#define BKV  128
#define NSPLIT 4
#define GELEMS (16 * NS)
// 32^-0.5 * log2(e): fold attention scale AND exp->exp2 conversion into Wq
#define QK_SCALE (0.17677669529663689f * 1.4426950408889634f)

__device__ __forceinline__ f32x4 mfma16(bf16x8 a, bf16x8 b, f32x4 c) {
  return __builtin_amdgcn_mfma_f32_16x16x32_bf16(a, b, c, 0, 0, 0);
}

// ---- fused: weight prep (blocks 0..191) + group-norm partial sums (192..287) ----
__global__ __launch_bounds__(256) void k_prep_stats(
    const float* __restrict__ qkv_w, const float* __restrict__ qkv_b,
    const float* __restrict__ proj_w, const float* __restrict__ x,
    bf16* __restrict__ wq, bf16* __restrict__ wp, float* __restrict__ bias_s,
    float* __restrict__ partials) {
  int bid = blockIdx.x;
  int tid = threadIdx.x;
  if (bid < 192) {
    int i = bid * 256 + tid;
    if (i < 3 * NC * NC) {
      float v = qkv_w[i];
      if (i < NC * NC) v *= QK_SCALE;          // q rows: scale + log2e fold
      wq[i] = (bf16)v;
    }
    if (i < NC * NC) wp[i] = (bf16)proj_w[i];
    if (i < 3 * NC) bias_s[i] = qkv_b[i] * ((i < NC) ? QK_SCALE : 1.0f);
    return;
  }
  int b = bid - 192;
  int g = b / 12, chunk = b % 12;
  float sum = 0.f, sq = 0.f;
  #pragma unroll
  for (int k = 0; k < 8; ++k) {
    int f4 = tid + k * 256;
    int c  = f4 >> 7;
    int s4 = f4 & 127;
    const float4 v = ((const float4*)x)[(size_t)(g * 16 + c) * (NS / 4) + chunk * 128 + s4];
    sum += v.x + v.y + v.z + v.w;
    sq  += v.x * v.x + v.y * v.y + v.z * v.z + v.w * v.w;
  }
  #pragma unroll
  for (int off = 32; off; off >>= 1) {
    sum += __shfl_down(sum, off, 64);
    sq  += __shfl_down(sq,  off, 64);
  }
  __shared__ float red[2][4];
  if ((tid & 63) == 0) { red[0][tid >> 6] = sum; red[1][tid >> 6] = sq; }
  __syncthreads();
  if (tid == 0) {
    partials[b * 2 + 0] = red[0][0] + red[0][1] + red[0][2] + red[0][3];
    partials[b * 2 + 1] = red[1][0] + red[1][1] + red[1][2] + red[1][3];
  }
}

// ---- apply group norm, write transposed xn_t[s][c] bf16 ----
__global__ __launch_bounds__(256) void k_gnapply(const float* __restrict__ x, const float* __restrict__ partials,
                                                 const float* __restrict__ gn_w, const float* __restrict__ gn_b,
                                                 bf16* __restrict__ xnt) {
  int bid = blockIdx.x;
  int c2 = bid & 63;
  int sb = bid >> 6;
  int c0 = c2 * 2;
  int g  = c0 >> 4;
  float sum = 0.f, sq = 0.f;
  #pragma unroll
  for (int i = 0; i < 12; ++i) {
    sum += partials[(g * 12 + i) * 2 + 0];
    sq  += partials[(g * 12 + i) * 2 + 1];
  }
  float mean = sum * (1.0f / GELEMS);
  float var  = sq  * (1.0f / GELEMS) - mean * mean;
  float rstd = rsqrtf(var + 1e-5f);
  int t = threadIdx.x;
  #pragma unroll
  for (int cc = 0; cc < 2; ++cc) {
    int c = c0 + cc;
    float wc = gn_w[c] * rstd;
    float bc = gn_b[c] - mean * wc;
    float2 v = ((const float2*)(x + (size_t)c * NS + sb * 512))[t];
    int s = sb * 512 + t * 2;
    xnt[(size_t)s * NC + c]       = (bf16)(v.x * wc + bc);
    xnt[(size_t)(s + 1) * NC + c] = (bf16)(v.y * wc + bc);
  }
}

// ---- QKV GEMM: q,k -> [h][s][32]; v -> transposed [h][c][s] ----
__global__ __launch_bounds__(256) void k_qkv(const bf16* __restrict__ wq, const bf16* __restrict__ xnt,
                                             const float* __restrict__ bias_s,
                                             bf16* __restrict__ qg, bf16* __restrict__ kg, bf16* __restrict__ vtg) {
  int ot = blockIdx.x;
  int st = blockIdx.y;
  int w = threadIdx.x >> 6, l = threadIdx.x & 63;
  int lr = l & 15, lg = l >> 4;
  int o_base = ot * 64 + (w >> 1) * 32;
  int s_base = st * 64 + (w & 1) * 32;
  f32x4 acc[2][2] = {};
  #pragma unroll
  for (int k0 = 0; k0 < NC; k0 += 32) {
    bf16x8 a[2], b[2];
    #pragma unroll
    for (int m = 0; m < 2; ++m)
      a[m] = *(const bf16x8*)(wq + (size_t)(o_base + m * 16 + lr) * NC + k0 + lg * 8);
    #pragma unroll
    for (int n = 0; n < 2; ++n)
      b[n] = *(const bf16x8*)(xnt + (size_t)(s_base + n * 16 + lr) * NC + k0 + lg * 8);
    #pragma unroll
    for (int m = 0; m < 2; ++m)
      #pragma unroll
      for (int n = 0; n < 2; ++n)
        acc[m][n] = mfma16(a[m], b[n], acc[m][n]);
  }
  #pragma unroll
  for (int m = 0; m < 2; ++m)
    #pragma unroll
    for (int n = 0; n < 2; ++n)
      #pragma unroll
      for (int r = 0; r < 4; ++r) {
        int o = o_base + m * 16 + lg * 4 + r;
        int s = s_base + n * 16 + lr;
        float v = acc[m][n][r] + bias_s[o];
        int rem = o & 127, head = rem >> 5, c32 = rem & 31;
        if (o < NC)          qg[((size_t)head * NS + s) * HD + c32] = (bf16)v;
        else if (o < 2 * NC) kg[((size_t)head * NS + s) * HD + c32] = (bf16)v;
        else                 vtg[((size_t)head * HD + c32) * NS + s] = (bf16)v;
      }
}

// ---- flash attention, swapped QK^T, no barriers, direct-global K/V, split-KV ----
__global__ __launch_bounds__(256, 4) void k_attn(
    const bf16* __restrict__ qg, const bf16* __restrict__ kg, const bf16* __restrict__ vtg,
    float* __restrict__ accP, float* __restrict__ ml) {
  int h = blockIdx.y, sp = blockIdx.z;
  int tid = threadIdx.x;
  int w = tid >> 6, l = tid & 63;
  int lr = l & 15, lg = l >> 4;
  int qrow0 = blockIdx.x * 64 + w * 16;

  __shared__ __align__(16) bf16 pb[4][16][136];   // per-wave P tile, A-frag layout

  const bf16* qp = qg + (size_t)h * NS * HD;
  const bf16* kp = kg + (size_t)h * NS * HD;
  const bf16* vp = vtg + (size_t)h * HD * NS;     // [c][s]

  // Q as B-operand of mfma(K,Q): lane holds Q[qrow=lr][k=lg*8+j] (pre-scaled)
  bf16x8 qf = *(const bf16x8*)(qp + (size_t)(qrow0 + lr) * HD + lg * 8);

  f32x4 acc0 = {}, acc1 = {};
  float m_r = -3.0e38f, l_r = 0.f;   // stats for qrow = lr (replicated over lg)
  const f32x4 zed = {};

  const int kv_beg = sp * (NS / NSPLIT);
  for (int kv = 0; kv < NS / NSPLIT; kv += BKV) {
    int kv0 = kv_beg + kv;
    // S^T tiles: sv[t] lane holds S[qrow=lr][key = kv0 + t*16 + lg*4 + r]
    f32x4 sv[8];
    #pragma unroll
    for (int t = 0; t < 8; ++t) {
      bf16x8 kf = *(const bf16x8*)(kp + (size_t)(kv0 + t * 16 + lr) * HD + lg * 8);
      sv[t] = mfma16(kf, qf, zed);
    }
    // lane-local max over 32 keys, then reduce across the 4 lanes sharing lr
    float mx = fmaxf(fmaxf(sv[0][0], sv[0][1]), fmaxf(sv[0][2], sv[0][3]));
    #pragma unroll
    for (int t = 1; t < 8; ++t)
      mx = fmaxf(mx, fmaxf(fmaxf(sv[t][0], sv[t][1]), fmaxf(sv[t][2], sv[t][3])));
    mx = fmaxf(mx, __shfl_xor(mx, 16, 64));
    mx = fmaxf(mx, __shfl_xor(mx, 32, 64));
    float mn  = fmaxf(m_r, mx);
    float esc = __builtin_amdgcn_exp2f(m_r - mn);
    l_r *= esc;
    float rs = 0.f;
    #pragma unroll
    for (int t = 0; t < 8; ++t) {
      #pragma unroll
      for (int r = 0; r < 4; ++r) sv[t][r] = __builtin_amdgcn_exp2f(sv[t][r] - mn);
      rs += (sv[t][0] + sv[t][1]) + (sv[t][2] + sv[t][3]);
    }
    rs += __shfl_xor(rs, 16, 64);
    rs += __shfl_xor(rs, 32, 64);
    l_r += rs;
    m_r = mn;
    // rescale O: acc row = qrow_local lg*4+r, fetch that row's esc
    #pragma unroll
    for (int r = 0; r < 4; ++r) {
      float e = __shfl(esc, lg * 4 + r, 64);
      acc0[r] *= e;
      acc1[r] *= e;
    }
    // P -> LDS in A-frag layout (per-wave, no barrier needed)
    #pragma unroll
    for (int t = 0; t < 8; ++t) {
      bf16x4 pk;
      pk[0] = (bf16)sv[t][0]; pk[1] = (bf16)sv[t][1];
      pk[2] = (bf16)sv[t][2]; pk[3] = (bf16)sv[t][3];
      *(bf16x4*)(&pb[w][lr][t * 16 + lg * 4]) = pk;
    }
    // PV: P A-frag from LDS, V B-frag direct from global [c][s]
    #pragma unroll
    for (int kk = 0; kk < 4; ++kk) {
      bf16x8 pf = *(const bf16x8*)(&pb[w][lr][kk * 32 + lg * 8]);
      bf16x8 v0 = *(const bf16x8*)(vp + (size_t)lr * NS + kv0 + kk * 32 + lg * 8);
      bf16x8 v1 = *(const bf16x8*)(vp + (size_t)(16 + lr) * NS + kv0 + kk * 32 + lg * 8);
      acc0 = mfma16(pf, v0, acc0);
      acc1 = mfma16(pf, v1, acc1);
    }
  }

  // store split partials: acc rows qrow_local = lg*4+r, cols lr / 16+lr
  float* ap = accP + (size_t)(h * NSPLIT + sp) * NS * HD;
  #pragma unroll
  for (int r = 0; r < 4; ++r) {
    size_t qrow = qrow0 + lg * 4 + r;
    ap[qrow * HD + lr]      = acc0[r];
    ap[qrow * HD + 16 + lr] = acc1[r];
  }
  if (lg == 0) {
    size_t qrow = qrow0 + lr;
    float* mp = ml + ((size_t)(h * NSPLIT + sp) * NS + qrow) * 2;
    mp[0] = m_r;
    mp[1] = l_r;
  }
}

// ---- combine split partials -> attn[s][128] bf16 ----
__global__ __launch_bounds__(256) void k_comb(const float* __restrict__ accP, const float* __restrict__ ml,
                                              bf16* __restrict__ attn) {
  int idx = blockIdx.x * 256 + threadIdx.x;
  int row = idx >> 3, cq = (idx & 7) * 4;
  int h = row / NS, s = row - h * NS;
  float mv[NSPLIT], lv[NSPLIT];
  float M = -3.0e38f;
  #pragma unroll
  for (int i = 0; i < NSPLIT; ++i) {
    mv[i] = ml[((size_t)(h * NSPLIT + i) * NS + s) * 2 + 0];
    lv[i] = ml[((size_t)(h * NSPLIT + i) * NS + s) * 2 + 1];
    M = fmaxf(M, mv[i]);
  }
  float L = 0.f, wgt[NSPLIT];
  #pragma unroll
  for (int i = 0; i < NSPLIT; ++i) {
    wgt[i] = __builtin_amdgcn_exp2f(mv[i] - M);
    L += lv[i] * wgt[i];
  }
  float inv = 1.0f / L;
  float o[4] = {0.f, 0.f, 0.f, 0.f};
  #pragma unroll
  for (int i = 0; i < NSPLIT; ++i) {
    const f32x4 a = *(const f32x4*)(accP + ((size_t)(h * NSPLIT + i) * NS + s) * HD + cq);
    #pragma unroll
    for (int j = 0; j < 4; ++j) o[j] += a[j] * wgt[i];
  }
  #pragma unroll
  for (int j = 0; j < 4; ++j)
    attn[(size_t)s * NC + h * HD + cq + j] = (bf16)(o[j] * inv);
}

// ---- proj GEMM + bias + residual + mask ----
__global__ __launch_bounds__(256) void k_proj(const bf16* __restrict__ wp, const bf16* __restrict__ attn,
                                              const float* __restrict__ proj_b, const float* __restrict__ x,
                                              const float* __restrict__ mask, float* __restrict__ out) {
  int ot = blockIdx.x;
  int st = blockIdx.y;
  int w = threadIdx.x >> 6, l = threadIdx.x & 63;
  int lr = l & 15, lg = l >> 4;
  int o_base = ot * 64 + (w >> 1) * 32;
  int s_base = st * 64 + (w & 1) * 32;
  f32x4 acc[2][2] = {};
  #pragma unroll
  for (int k0 = 0; k0 < NC; k0 += 32) {
    bf16x8 a[2], b[2];
    #pragma unroll
    for (int m = 0; m < 2; ++m)
      a[m] = *(const bf16x8*)(wp + (size_t)(o_base + m * 16 + lr) * NC + k0 + lg * 8);
    #pragma unroll
    for (int n = 0; n < 2; ++n)
      b[n] = *(const bf16x8*)(attn + (size_t)(s_base + n * 16 + lr) * NC + k0 + lg * 8);
    #pragma unroll
    for (int m = 0; m < 2; ++m)
      #pragma unroll
      for (int n = 0; n < 2; ++n)
        acc[m][n] = mfma16(a[m], b[n], acc[m][n]);
  }
  #pragma unroll
  for (int m = 0; m < 2; ++m)
    #pragma unroll
    for (int n = 0; n < 2; ++n)
      #pragma unroll
      for (int r = 0; r < 4; ++r) {
        int o = o_base + m * 16 + lg * 4 + r;
        int s = s_base + n * 16 + lr;
        float v = acc[m][n][r] + proj_b[o] + x[(size_t)o * NS + s];
        out[(size_t)o * NS + s] = v * mask[s];
      }
}

extern "C" void kernel_launch(void* const* d_in, const int* in_sizes, int n_in,
                              void* d_out, int out_size, void* d_ws, size_t ws_size,
                              hipStream_t stream) {
  const float* x      = (const float*)d_in[0];
  const float* mask   = (const float*)d_in[1];
  const float* gn_w   = (const float*)d_in[2];
  const float* gn_b   = (const float*)d_in[3];
  const float* qkv_w  = (const float*)d_in[4];
  const float* qkv_b  = (const float*)d_in[5];
  const float* proj_w = (const float*)d_in[6];
  const float* proj_b = (const float*)d_in[7];

  char* ws = (char*)d_ws;
  float* partials = (float*)(ws + 0);            //    768 B
  float* bias_s   = (float*)(ws + 1024);         //   1536 B
  bf16*  wq       = (bf16*)(ws + 4096);          //  98304 B
  bf16*  wp       = (bf16*)(ws + 102400);        //  32768 B
  bf16*  xnt      = (bf16*)(ws + 135168);        // 1.50 MB [s][c]
  bf16*  qg       = (bf16*)(ws + 1708032);       // 1.50 MB [h][s][32]
  bf16*  kg       = (bf16*)(ws + 3280896);       // 1.50 MB [h][s][32]
  bf16*  vtg      = (bf16*)(ws + 4853760);       // 1.50 MB [h][c][s]
  bf16*  attn     = (bf16*)(ws + 6426624);       // 1.50 MB [s][c]
  float* accP     = (float*)(ws + 7999488);      // 12.58 MB [h][sp][s][32]
  float* ml       = (float*)(ws + 20582400);     // 786 KB  [h][sp][s][2]
  float* out      = (float*)d_out;

  k_prep_stats<<<288, 256, 0, stream>>>(qkv_w, qkv_b, proj_w, x, wq, wp, bias_s, partials);
  k_gnapply   <<<768, 256, 0, stream>>>(x, partials, gn_w, gn_b, xnt);
  k_qkv       <<<dim3(6, 96), 256, 0, stream>>>(wq, xnt, bias_s, qg, kg, vtg);
  k_attn      <<<dim3(96, 4, NSPLIT), 256, 0, stream>>>(qg, kg, vtg, accP, ml);
  k_comb      <<<768, 256, 0, stream>>>(accP, ml, attn);
  k_proj      <<<dim3(2, 96), 256, 0, stream>>>(wp, attn, proj_b, x, mask, out);
  hipMemcpyAsync(out + (size_t)NC * NS, mask, NS * sizeof(float),
                 hipMemcpyDeviceToDevice, stream);
}

// Round 3
// 136.957 us; speedup vs baseline: 1.4365x; 1.0929x over previous
//
#include <hip/hip_runtime.h>
#include <hip/hip_bf16.h>
#include <cstddef>

typedef __bf16 bf16;
typedef __bf16 bf16x4 __attribute__((ext_vector_type(4)));
typedef __bf16 bf16x8 __attribute__((ext_vector_type(8)));
typedef float  f32x4  __attribute__((ext_vector_type(4)));

#define NC   128
#define NS   6144
#define HD   32
#define BKV  128
#define NSPLIT 8
#define GELEMS (16 * NS)
// 32^-0.5 * log2(e): fold attention scale AND exp->exp2 conversion into Wq
#define QK_SCALE (0.17677669529663689f * 1.4426950408889634f)

__device__ __forceinline__ f32x4 mfma16(bf16x8 a, bf16x8 b, f32x4 c) {
  return __builtin_amdgcn_mfma_f32_16x16x32_bf16(a, b, c, 0, 0, 0);
}

// ---- fused: weight prep (blocks 0..191) + group-norm partial sums (192..287) ----
__global__ __launch_bounds__(256) void k_prep_stats(
    const float* __restrict__ qkv_w, const float* __restrict__ qkv_b,
    const float* __restrict__ proj_w, const float* __restrict__ x,
    bf16* __restrict__ wq, bf16* __restrict__ wp, float* __restrict__ bias_s,
    float* __restrict__ partials) {
  int bid = blockIdx.x;
  int tid = threadIdx.x;
  if (bid < 192) {
    int i = bid * 256 + tid;
    if (i < 3 * NC * NC) {
      float v = qkv_w[i];
      if (i < NC * NC) v *= QK_SCALE;
      wq[i] = (bf16)v;
    }
    if (i < NC * NC) wp[i] = (bf16)proj_w[i];
    if (i < 3 * NC) bias_s[i] = qkv_b[i] * ((i < NC) ? QK_SCALE : 1.0f);
    return;
  }
  int b = bid - 192;
  int g = b / 12, chunk = b % 12;
  float sum = 0.f, sq = 0.f;
  #pragma unroll
  for (int k = 0; k < 8; ++k) {
    int f4 = tid + k * 256;
    int c  = f4 >> 7;
    int s4 = f4 & 127;
    const float4 v = ((const float4*)x)[(size_t)(g * 16 + c) * (NS / 4) + chunk * 128 + s4];
    sum += v.x + v.y + v.z + v.w;
    sq  += v.x * v.x + v.y * v.y + v.z * v.z + v.w * v.w;
  }
  #pragma unroll
  for (int off = 32; off; off >>= 1) {
    sum += __shfl_down(sum, off, 64);
    sq  += __shfl_down(sq,  off, 64);
  }
  __shared__ float red[2][4];
  if ((tid & 63) == 0) { red[0][tid >> 6] = sum; red[1][tid >> 6] = sq; }
  __syncthreads();
  if (tid == 0) {
    partials[b * 2 + 0] = red[0][0] + red[0][1] + red[0][2] + red[0][3];
    partials[b * 2 + 1] = red[1][0] + red[1][1] + red[1][2] + red[1][3];
  }
}

// ---- apply group norm: one thread per (s, c-octet), coalesced bf16x8 stores ----
__global__ __launch_bounds__(256) void k_gnapply(const float* __restrict__ x, const float* __restrict__ partials,
                                                 const float* __restrict__ gn_w, const float* __restrict__ gn_b,
                                                 bf16* __restrict__ xnt) {
  int tid = blockIdx.x * 256 + threadIdx.x;
  int s  = tid >> 4;
  int c0 = (tid & 15) * 8;
  int g  = c0 >> 4;
  float sum = 0.f, sq = 0.f;
  #pragma unroll
  for (int i = 0; i < 12; ++i) {
    sum += partials[(g * 12 + i) * 2 + 0];
    sq  += partials[(g * 12 + i) * 2 + 1];
  }
  float mean = sum * (1.0f / GELEMS);
  float var  = sq  * (1.0f / GELEMS) - mean * mean;
  float rstd = rsqrtf(var + 1e-5f);
  bf16x8 o;
  #pragma unroll
  for (int j = 0; j < 8; ++j) {
    int c = c0 + j;
    float wc = gn_w[c] * rstd;
    float bc = gn_b[c] - mean * wc;
    o[j] = (bf16)(x[(size_t)c * NS + s] * wc + bc);
  }
  *(bf16x8*)(xnt + (size_t)s * NC + c0) = o;
}

// ---- QKV GEMM: q,k -> [h][s][32]; v -> transposed [h][c][s] ----
__global__ __launch_bounds__(256) void k_qkv(const bf16* __restrict__ wq, const bf16* __restrict__ xnt,
                                             const float* __restrict__ bias_s,
                                             bf16* __restrict__ qg, bf16* __restrict__ kg, bf16* __restrict__ vtg) {
  int ot = blockIdx.x;
  int st = blockIdx.y;
  int w = threadIdx.x >> 6, l = threadIdx.x & 63;
  int lr = l & 15, lg = l >> 4;
  int o_base = ot * 64 + (w >> 1) * 32;
  int s_base = st * 64 + (w & 1) * 32;
  f32x4 acc[2][2] = {};
  #pragma unroll
  for (int k0 = 0; k0 < NC; k0 += 32) {
    bf16x8 a[2], b[2];
    #pragma unroll
    for (int m = 0; m < 2; ++m)
      a[m] = *(const bf16x8*)(wq + (size_t)(o_base + m * 16 + lr) * NC + k0 + lg * 8);
    #pragma unroll
    for (int n = 0; n < 2; ++n)
      b[n] = *(const bf16x8*)(xnt + (size_t)(s_base + n * 16 + lr) * NC + k0 + lg * 8);
    #pragma unroll
    for (int m = 0; m < 2; ++m)
      #pragma unroll
      for (int n = 0; n < 2; ++n)
        acc[m][n] = mfma16(a[m], b[n], acc[m][n]);
  }
  #pragma unroll
  for (int m = 0; m < 2; ++m)
    #pragma unroll
    for (int n = 0; n < 2; ++n)
      #pragma unroll
      for (int r = 0; r < 4; ++r) {
        int o = o_base + m * 16 + lg * 4 + r;
        int s = s_base + n * 16 + lr;
        float v = acc[m][n][r] + bias_s[o];
        int rem = o & 127, head = rem >> 5, c32 = rem & 31;
        if (o < NC)          qg[((size_t)head * NS + s) * HD + c32] = (bf16)v;
        else if (o < 2 * NC) kg[((size_t)head * NS + s) * HD + c32] = (bf16)v;
        else                 vtg[((size_t)head * HD + c32) * NS + s] = (bf16)v;
      }
}

// ---- flash attention: swapped QK^T AND swapped PV (O^T), lane-local rescale,
//      XOR-swizzled P buffer, V prefetch before softmax, split-KV x8 ----
__global__ __launch_bounds__(256, 4) void k_attn(
    const bf16* __restrict__ qg, const bf16* __restrict__ kg, const bf16* __restrict__ vtg,
    bf16* __restrict__ accP, float* __restrict__ ml) {
  const int h = blockIdx.y, sp = blockIdx.z;
  const int tid = threadIdx.x;
  const int w = tid >> 6, l = tid & 63;
  const int lr = l & 15, lg = l >> 4;
  const int qrow0 = blockIdx.x * 64 + w * 16;

  __shared__ __align__(16) char pbs[4 * 4096];   // per-wave 16-row x 256B P tile
  char* pw = pbs + w * 4096;
  const int swz   = (lr & 7) << 4;
  const int wbase = lr * 256 + lg * 8;
  const int rbase = lr * 256 + lg * 16;

  const bf16* qp = qg + (size_t)h * NS * HD;
  const bf16* kp = kg + (size_t)h * NS * HD;
  const bf16* vp = vtg + (size_t)h * HD * NS;

  // Q as B-operand of mfma(K,Q): lane holds Q[qrow0+lr][lg*8+j] (pre-scaled)
  bf16x8 qf = *(const bf16x8*)(qp + (size_t)(qrow0 + lr) * HD + lg * 8);

  f32x4 acc0 = {}, acc1 = {};           // O^T: rows c, col q = lr (lane-local stats!)
  float m_r = -3.0e38f, l_r = 0.f;
  const f32x4 zed = {};

  const int kv_beg = sp * (NS / NSPLIT);
  for (int kv = 0; kv < NS / NSPLIT; kv += BKV) {
    const int kv0 = kv_beg + kv;
    const bf16* kc  = kp + (size_t)(kv0 + lr) * HD + lg * 8;
    const bf16* vc0 = vp + (size_t)lr * NS + kv0 + lg * 8;
    const bf16* vc1 = vc0 + (size_t)16 * NS;

    // QK^T: sv[t] lane holds S[key = kv0+t*16+lg*4+r][q = lr]
    f32x4 sv[8];
    #pragma unroll
    for (int t = 0; t < 8; ++t)
      sv[t] = mfma16(*(const bf16x8*)(kc + t * 16 * HD), qf, zed);

    // V prefetch (consumed after softmax; latency hides under the exps)
    bf16x8 vf0[4], vf1[4];
    #pragma unroll
    for (int kk = 0; kk < 4; ++kk) {
      vf0[kk] = *(const bf16x8*)(vc0 + kk * 32);
      vf1[kk] = *(const bf16x8*)(vc1 + kk * 32);
    }

    // online softmax for q = lr (32 lane-local keys, then reduce over lg)
    float mx = fmaxf(fmaxf(sv[0][0], sv[0][1]), fmaxf(sv[0][2], sv[0][3]));
    #pragma unroll
    for (int t = 1; t < 8; ++t)
      mx = fmaxf(mx, fmaxf(fmaxf(sv[t][0], sv[t][1]), fmaxf(sv[t][2], sv[t][3])));
    mx = fmaxf(mx, __shfl_xor(mx, 16, 64));
    mx = fmaxf(mx, __shfl_xor(mx, 32, 64));
    float mn  = fmaxf(m_r, mx);
    float esc = __builtin_amdgcn_exp2f(m_r - mn);
    float rs = 0.f;
    #pragma unroll
    for (int t = 0; t < 8; ++t) {
      #pragma unroll
      for (int r = 0; r < 4; ++r) sv[t][r] = __builtin_amdgcn_exp2f(sv[t][r] - mn);
      rs += (sv[t][0] + sv[t][1]) + (sv[t][2] + sv[t][3]);
    }
    rs += __shfl_xor(rs, 16, 64);
    rs += __shfl_xor(rs, 32, 64);
    l_r = l_r * esc + rs;
    m_r = mn;
    // O^T cols are q=lr: rescale is lane-local, no shuffle
    #pragma unroll
    for (int r = 0; r < 4; ++r) { acc0[r] *= esc; acc1[r] *= esc; }

    // P^T -> LDS (swizzled, per-wave region, no barrier)
    #pragma unroll
    for (int t = 0; t < 8; ++t) {
      bf16x4 pk;
      pk[0] = (bf16)sv[t][0]; pk[1] = (bf16)sv[t][1];
      pk[2] = (bf16)sv[t][2]; pk[3] = (bf16)sv[t][3];
      *(bf16x4*)(pw + ((wbase + t * 32) ^ swz)) = pk;
    }

    // PV as O^T = mfma(V^T, P^T): same per-lane P data, acc col = q = lr
    #pragma unroll
    for (int kk = 0; kk < 4; ++kk) {
      bf16x8 pf = *(const bf16x8*)(pw + ((rbase + kk * 64) ^ swz));
      acc0 = mfma16(vf0[kk], pf, acc0);
      acc1 = mfma16(vf1[kk], pf, acc1);
    }
  }

  // store unnormalized O^T partials as bf16: [q][c], lane writes c=lg*4..+3 (tiles 0,1)
  bf16* ap = accP + (size_t)(h * NSPLIT + sp) * NS * HD + (size_t)(qrow0 + lr) * HD;
  bf16x4 o0, o1;
  #pragma unroll
  for (int r = 0; r < 4; ++r) { o0[r] = (bf16)acc0[r]; o1[r] = (bf16)acc1[r]; }
  *(bf16x4*)(ap + lg * 4)      = o0;
  *(bf16x4*)(ap + 16 + lg * 4) = o1;
  if (lg == 0) {
    float2 s2; s2.x = m_r; s2.y = l_r;
    ((float2*)ml)[(size_t)(h * NSPLIT + sp) * NS + qrow0 + lr] = s2;
  }
}

// ---- combine split partials -> attn[s][128] bf16 ----
__global__ __launch_bounds__(256) void k_comb(const bf16* __restrict__ accP, const float* __restrict__ ml,
                                              bf16* __restrict__ attn) {
  int idx = blockIdx.x * 256 + threadIdx.x;
  int row = idx >> 3, cq = (idx & 7) * 4;
  int h = row / NS, s = row - h * NS;
  float mv[NSPLIT], lv[NSPLIT];
  float M = -3.0e38f;
  #pragma unroll
  for (int i = 0; i < NSPLIT; ++i) {
    float2 t = ((const float2*)ml)[(size_t)(h * NSPLIT + i) * NS + s];
    mv[i] = t.x; lv[i] = t.y;
    M = fmaxf(M, mv[i]);
  }
  float L = 0.f, wgt[NSPLIT];
  #pragma unroll
  for (int i = 0; i < NSPLIT; ++i) {
    wgt[i] = __builtin_amdgcn_exp2f(mv[i] - M);
    L += lv[i] * wgt[i];
  }
  float inv = 1.0f / L;
  float o[4] = {0.f, 0.f, 0.f, 0.f};
  #pragma unroll
  for (int i = 0; i < NSPLIT; ++i) {
    bf16x4 a = *(const bf16x4*)(accP + ((size_t)(h * NSPLIT + i) * NS + s) * HD + cq);
    #pragma unroll
    for (int j = 0; j < 4; ++j) o[j] += (float)a[j] * wgt[i];
  }
  bf16x4 ov;
  #pragma unroll
  for (int j = 0; j < 4; ++j) ov[j] = (bf16)(o[j] * inv);
  *(bf16x4*)(attn + (size_t)s * NC + h * HD + cq) = ov;
}

// ---- proj GEMM + bias + residual + mask ----
__global__ __launch_bounds__(256) void k_proj(const bf16* __restrict__ wp, const bf16* __restrict__ attn,
                                              const float* __restrict__ proj_b, const float* __restrict__ x,
                                              const float* __restrict__ mask, float* __restrict__ out) {
  int ot = blockIdx.x;
  int st = blockIdx.y;
  int w = threadIdx.x >> 6, l = threadIdx.x & 63;
  int lr = l & 15, lg = l >> 4;
  int o_base = ot * 64 + (w >> 1) * 32;
  int s_base = st * 64 + (w & 1) * 32;
  f32x4 acc[2][2] = {};
  #pragma unroll
  for (int k0 = 0; k0 < NC; k0 += 32) {
    bf16x8 a[2], b[2];
    #pragma unroll
    for (int m = 0; m < 2; ++m)
      a[m] = *(const bf16x8*)(wp + (size_t)(o_base + m * 16 + lr) * NC + k0 + lg * 8);
    #pragma unroll
    for (int n = 0; n < 2; ++n)
      b[n] = *(const bf16x8*)(attn + (size_t)(s_base + n * 16 + lr) * NC + k0 + lg * 8);
    #pragma unroll
    for (int m = 0; m < 2; ++m)
      #pragma unroll
      for (int n = 0; n < 2; ++n)
        acc[m][n] = mfma16(a[m], b[n], acc[m][n]);
  }
  #pragma unroll
  for (int m = 0; m < 2; ++m)
    #pragma unroll
    for (int n = 0; n < 2; ++n)
      #pragma unroll
      for (int r = 0; r < 4; ++r) {
        int o = o_base + m * 16 + lg * 4 + r;
        int s = s_base + n * 16 + lr;
        float v = acc[m][n][r] + proj_b[o] + x[(size_t)o * NS + s];
        out[(size_t)o * NS + s] = v * mask[s];
      }
}

extern "C" void kernel_launch(void* const* d_in, const int* in_sizes, int n_in,
                              void* d_out, int out_size, void* d_ws, size_t ws_size,
                              hipStream_t stream) {
  const float* x      = (const float*)d_in[0];
  const float* mask   = (const float*)d_in[1];
  const float* gn_w   = (const float*)d_in[2];
  const float* gn_b   = (const float*)d_in[3];
  const float* qkv_w  = (const float*)d_in[4];
  const float* qkv_b  = (const float*)d_in[5];
  const float* proj_w = (const float*)d_in[6];
  const float* proj_b = (const float*)d_in[7];

  char* ws = (char*)d_ws;
  float* partials = (float*)(ws + 0);            //     768 B
  float* bias_s   = (float*)(ws + 1024);         //    1536 B
  bf16*  wq       = (bf16*)(ws + 4096);          //   98304 B
  bf16*  wp       = (bf16*)(ws + 102400);        //   32768 B
  bf16*  qg       = (bf16*)(ws + 135168);        // 1.50 MB [h][s][32]
  bf16*  kg       = (bf16*)(ws + 1708032);       // 1.50 MB [h][s][32]
  bf16*  vtg      = (bf16*)(ws + 3280896);       // 1.50 MB [h][c][s]
  bf16*  attn     = (bf16*)(ws + 4853760);       // 1.50 MB [s][c]
  bf16*  xnt      = (bf16*)(ws + 6426624);       // 1.50 MB [s][c] (dead after k_qkv)
  bf16*  accP     = (bf16*)(ws + 6426624);       // 12.58 MB [h][sp][s][32] (overlaps xnt)
  float* ml       = (float*)(ws + 19009536);     // 1.50 MB [h][sp][s][2]  -> ends 20582400
  float* out      = (float*)d_out;

  k_prep_stats<<<288, 256, 0, stream>>>(qkv_w, qkv_b, proj_w, x, wq, wp, bias_s, partials);
  k_gnapply   <<<384, 256, 0, stream>>>(x, partials, gn_w, gn_b, xnt);
  k_qkv       <<<dim3(6, 96), 256, 0, stream>>>(wq, xnt, bias_s, qg, kg, vtg);
  k_attn      <<<dim3(96, 4, NSPLIT), 256, 0, stream>>>(qg, kg, vtg, accP, ml);
  k_comb      <<<768, 256, 0, stream>>>(accP, ml, attn);
  k_proj      <<<dim3(2, 96), 256, 0, stream>>>(wp, attn, proj_b, x, mask, out);
  hipMemcpyAsync(out + (size_t)NC * NS, mask, NS * sizeof(float),
                 hipMemcpyDeviceToDevice, stream);
}